// Round 7
// baseline (118.661 us; speedup 1.0000x reference)
//
#include <hip/hip_runtime.h>
#include <stdint.h>

typedef __attribute__((ext_vector_type(8))) short bf16x8;
typedef __attribute__((ext_vector_type(4))) float f32x4;
typedef __attribute__((ext_vector_type(16))) float f32x16;

#define B_ 8192
#define F_ 1024
#define E_ 2048
#define H_ 16
#define D_ 64

__device__ __forceinline__ unsigned short f2bf(float f) {
    union { float f; unsigned u; } v; v.f = f;
    unsigned u = v.u;
    unsigned r = (u + 0x7FFFu + ((u >> 16) & 1u)) >> 16;
    return (unsigned short)r;
}

__device__ __forceinline__ unsigned cvtpk(float a, float b) {
    unsigned r;
    asm("v_cvt_pk_bf16_f32 %0, %1, %2" : "=v"(r) : "v"(a), "v"(b));
    return r;
}

__device__ __forceinline__ void gll16(const void* g, void* l) {
    __builtin_amdgcn_global_load_lds(
        (const __attribute__((address_space(1))) unsigned int*)g,
        (__attribute__((address_space(3))) unsigned int*)l, 16, 0, 0);
}

// ---- L1: cast-swizzle x (blocks 0..4095) | Gram G=K.K^T (4096..4099, wave/head)
//          | rowsums rs[hd]=sum_e K (4100..4131) ----
__global__ __launch_bounds__(256) void k_prep(const float* __restrict__ x,
                                              const float* __restrict__ emb,
                                              unsigned short* __restrict__ xb,
                                              float* __restrict__ G,
                                              float* __restrict__ rs) {
    int bid = blockIdx.x, tid = threadIdx.x;
    if (bid < 4096) {
        int t = bid * 256 + tid;
        int row = t >> 7;                 // 128 chunks of 8 elems per 1024-col row
        int c8  = t & 127;
        int colbyte = c8 * 16;
        const float4* s4 = (const float4*)(x + (size_t)row * 1024 + c8 * 8);
        float4 a = s4[0], b = s4[1];
        unsigned short tmp[8];
        tmp[0] = f2bf(a.x); tmp[1] = f2bf(a.y); tmp[2] = f2bf(a.z); tmp[3] = f2bf(a.w);
        tmp[4] = f2bf(b.x); tmp[5] = f2bf(b.y); tmp[6] = f2bf(b.z); tmp[7] = f2bf(b.w);
        int dstbyte = (colbyte & ~127) | ((colbyte & 127) ^ ((row & 7) << 4));
        *(uint4*)((char*)xb + (size_t)row * 2048 + dstbyte) = *(const uint4*)tmp;
    } else if (bid < 4100) {
        // Gram: one wave per head. G[h][d1][d2] = sum_e K[d1,e]*K[d2,e]
        int lane = tid & 63, w = tid >> 6;
        int hi = lane >> 5, lo = lane & 31;
        int h = (bid - 4096) * 4 + w;
        f32x16 acc[2][2];
#pragma unroll
        for (int i = 0; i < 2; ++i)
#pragma unroll
            for (int j = 0; j < 2; ++j) acc[i][j] = (f32x16)0.f;
        for (int step = 0; step < 128; ++step) {
            int e0 = step * 16;
            union U { unsigned u[4]; bf16x8 v; } fr[2];
#pragma unroll
            for (int dt = 0; dt < 2; ++dt) {
                const float* p = emb + (size_t)(h * 64 + dt * 32 + lo) * 2048 + e0 + hi * 8;
                float4 a = *(const float4*)p;
                float4 b = *(const float4*)(p + 4);
                fr[dt].u[0] = cvtpk(a.x, a.y); fr[dt].u[1] = cvtpk(a.z, a.w);
                fr[dt].u[2] = cvtpk(b.x, b.y); fr[dt].u[3] = cvtpk(b.z, b.w);
            }
#pragma unroll
            for (int dA = 0; dA < 2; ++dA)
#pragma unroll
                for (int dB = 0; dB < 2; ++dB)
                    acc[dA][dB] = __builtin_amdgcn_mfma_f32_32x32x16_bf16(
                        fr[dA].v, fr[dB].v, acc[dA][dB], 0, 0, 0);
        }
#pragma unroll
        for (int dA = 0; dA < 2; ++dA)
#pragma unroll
            for (int dB = 0; dB < 2; ++dB)
#pragma unroll
                for (int r = 0; r < 16; ++r) {
                    int d1 = dA * 32 + (r & 3) + 8 * (r >> 2) + 4 * hi;
                    int d2 = dB * 32 + lo;
                    G[h * 4096 + d1 * 64 + d2] = acc[dA][dB][r];
                }
    } else {
        // rowsums: 32 blocks x 32 rows; wave handles 8 rows
        int lane = tid & 63, w = tid >> 6;
        const float4* e4 = (const float4*)emb;
#pragma unroll
        for (int rr = 0; rr < 8; ++rr) {
            int row = (bid - 4100) * 32 + w * 8 + rr;
            float s = 0.f;
#pragma unroll
            for (int i = 0; i < 8; ++i) {
                float4 t = e4[(size_t)row * 512 + i * 64 + lane];
                s += t.x + t.y + t.z + t.w;
            }
#pragma unroll
            for (int m = 32; m; m >>= 1) s += __shfl_xor(s, m, 64);
            if (lane == 0) rs[row] = s;
        }
    }
}

// ---- L2: W''[n][k] = (1/32) sum_d' W[h64+d'][k]*G[h][d'][d]  (bf16, swizzled)
//          + b''[n] = 0.5*rs[n] + (1/32) sum_d' pb[h64+d']*G[h][d'][d] ----
__global__ __launch_bounds__(256) void k_wpp(const float* __restrict__ W,
                                             const float* __restrict__ G,
                                             const float* __restrict__ pb,
                                             const float* __restrict__ rs,
                                             unsigned short* __restrict__ wbpp,
                                             float* __restrict__ bpp) {
    int bid = blockIdx.x, tid = threadIdx.x;
    if (bid < 128) {
        int lane = tid & 63, w = tid >> 6;
        int wt = bid * 4 + w;                  // 512 wave-tasks
        int h = wt >> 5, nt = wt & 31;
        int hi = lane >> 5, lo = lane & 31;
        union U { unsigned u[4]; bf16x8 v; } af[2][4], bfr[4];
#pragma unroll
        for (int mt = 0; mt < 2; ++mt)
#pragma unroll
            for (int ks = 0; ks < 4; ++ks) {
                float g[8];
#pragma unroll
                for (int j = 0; j < 8; ++j)
                    g[j] = G[h * 4096 + (ks * 16 + hi * 8 + j) * 64 + mt * 32 + lo] * 0.03125f;
                af[mt][ks].u[0] = cvtpk(g[0], g[1]); af[mt][ks].u[1] = cvtpk(g[2], g[3]);
                af[mt][ks].u[2] = cvtpk(g[4], g[5]); af[mt][ks].u[3] = cvtpk(g[6], g[7]);
            }
#pragma unroll
        for (int ks = 0; ks < 4; ++ks) {
            float b[8];
#pragma unroll
            for (int j = 0; j < 8; ++j)
                b[j] = W[(size_t)(h * 64 + ks * 16 + hi * 8 + j) * 1024 + nt * 32 + lo];
            bfr[ks].u[0] = cvtpk(b[0], b[1]); bfr[ks].u[1] = cvtpk(b[2], b[3]);
            bfr[ks].u[2] = cvtpk(b[4], b[5]); bfr[ks].u[3] = cvtpk(b[6], b[7]);
        }
        f32x16 acc[2];
#pragma unroll
        for (int mt = 0; mt < 2; ++mt) acc[mt] = (f32x16)0.f;
#pragma unroll
        for (int mt = 0; mt < 2; ++mt)
#pragma unroll
            for (int ks = 0; ks < 4; ++ks)
                acc[mt] = __builtin_amdgcn_mfma_f32_32x32x16_bf16(
                    af[mt][ks].v, bfr[ks].v, acc[mt], 0, 0, 0);
#pragma unroll
        for (int mt = 0; mt < 2; ++mt)
#pragma unroll
            for (int r = 0; r < 16; ++r) {
                int d = mt * 32 + (r & 3) + 8 * (r >> 2) + 4 * hi;
                int nrow = h * 64 + d;
                int k = nt * 32 + lo;
                int colbyte = k * 2;
                int byte = (colbyte & ~127) | ((colbyte & 127) ^ ((nrow & 7) << 4));
                *(unsigned short*)((char*)wbpp + (size_t)nrow * 2048 + byte) =
                    f2bf(acc[mt][r]);
            }
    } else {
        int n = (bid - 128) * 256 + tid;       // 0..1023
        int h = n >> 6, d = n & 63;
        float s = 0.f;
        for (int dp = 0; dp < 64; ++dp)
            s += pb[h * 64 + dp] * G[h * 4096 + dp * 64 + d];
        bpp[n] = 0.03125f * s + 0.5f * rs[n];
    }
}

// ---- L3: out = x @ W''^T + b''  (f32 out), m97-style 128x128 GEMM ----
__global__ __launch_bounds__(256) void k_final(const unsigned short* __restrict__ xb,
                                               const unsigned short* __restrict__ wb,
                                               const float* __restrict__ bias,
                                               float* __restrict__ O) {
    __shared__ alignas(16) short As[128 * 64];
    __shared__ alignas(16) short Bs[128 * 64];
    int tid = threadIdx.x;
    int lane = tid & 63, w = tid >> 6;
    int q = lane >> 4, c = lane & 15;
    int nt = blockIdx.x & 7, mt = blockIdx.x >> 3;
    int m0 = mt * 128, n0 = nt * 128;
    int wm = w >> 1, wn = w & 1;

    f32x4 acc[4][4];
#pragma unroll
    for (int i = 0; i < 4; ++i)
#pragma unroll
        for (int j = 0; j < 4; ++j) acc[i][j] = (f32x4)0.f;

    for (int kt = 0; kt < F_ / 64; ++kt) {
        int k0b = kt * 128;
#pragma unroll
        for (int p = 0; p < 4; ++p) {
            int o = (tid + p * 256) * 16;
            int r = o >> 7, cb = o & 127;
            gll16((const char*)xb + (size_t)(m0 + r) * 2048 + k0b + cb, (char*)As + o);
        }
#pragma unroll
        for (int p = 0; p < 4; ++p) {
            int o = (tid + p * 256) * 16;
            int r = o >> 7, cb = o & 127;
            gll16((const char*)wb + (size_t)(n0 + r) * 2048 + k0b + cb, (char*)Bs + o);
        }
        __syncthreads();

        bf16x8 af[4][2], bfr[4][2];
#pragma unroll
        for (int mf = 0; mf < 4; ++mf)
#pragma unroll
            for (int ks = 0; ks < 2; ++ks) {
                int r  = wm * 64 + mf * 16 + c;
                int kb = (16 * q + 64 * ks) ^ ((r & 7) << 4);
                af[mf][ks] = *(const bf16x8*)((const char*)As + r * 128 + kb);
            }
#pragma unroll
        for (int nf = 0; nf < 4; ++nf)
#pragma unroll
            for (int ks = 0; ks < 2; ++ks) {
                int r  = wn * 64 + nf * 16 + c;
                int kb = (16 * q + 64 * ks) ^ ((r & 7) << 4);
                bfr[nf][ks] = *(const bf16x8*)((const char*)Bs + r * 128 + kb);
            }
#pragma unroll
        for (int ks = 0; ks < 2; ++ks)
#pragma unroll
            for (int mf = 0; mf < 4; ++mf)
#pragma unroll
                for (int nf = 0; nf < 4; ++nf)
                    acc[mf][nf] = __builtin_amdgcn_mfma_f32_16x16x32_bf16(
                        af[mf][ks], bfr[nf][ks], acc[mf][nf], 0, 0, 0);
        __syncthreads();
    }

#pragma unroll
    for (int mf = 0; mf < 4; ++mf)
#pragma unroll
        for (int nf = 0; nf < 4; ++nf) {
            int n = n0 + wn * 64 + nf * 16 + c;
            float bv = bias[n];
#pragma unroll
            for (int r = 0; r < 4; ++r) {
                int m = m0 + wm * 64 + mf * 16 + q * 4 + r;
                O[(size_t)m * F_ + n] = acc[mf][nf][r] + bv;
            }
        }
}

extern "C" void kernel_launch(void* const* d_in, const int* in_sizes, int n_in,
                              void* d_out, int out_size, void* d_ws, size_t ws_size,
                              hipStream_t stream) {
    const float* x   = (const float*)d_in[0];
    const float* pw  = (const float*)d_in[1];
    const float* pb  = (const float*)d_in[2];
    const float* emb = (const float*)d_in[3];

    char* ws = (char*)d_ws;
    unsigned short* xb   = (unsigned short*)(ws);                 // 16 MB, swizzled bf16 x
    unsigned short* wbpp = (unsigned short*)(ws + 16777216);      //  2 MB, swizzled bf16 W''
    float*          G    = (float*)(ws + 18874368);               // 256 KB Gram (f32)
    float*          rs   = (float*)(ws + 19136512);               //  4 KB rowsums
    float*          bpp  = (float*)(ws + 19140608);               //  4 KB b''

    k_prep<<<4132, 256, 0, stream>>>(x, emb, xb, G, rs);
    k_wpp<<<132, 256, 0, stream>>>(pw, G, pb, rs, wbpp, bpp);
    k_final<<<512, 256, 0, stream>>>(xb, wbpp, bpp, (float*)d_out);
}

// Round 8
// 58.223 us; speedup vs baseline: 2.0380x; 2.0380x over previous
//
#include <hip/hip_runtime.h>
#include <stdint.h>

typedef __attribute__((ext_vector_type(8))) short bf16x8;
typedef __attribute__((ext_vector_type(4))) float f32x4;
typedef __attribute__((ext_vector_type(16))) float f32x16;

#define B_ 8192
#define F_ 1024
#define E_ 2048
#define H_ 16
#define D_ 64

__device__ __forceinline__ unsigned short f2bf(float f) {
    union { float f; unsigned u; } v; v.f = f;
    unsigned u = v.u;
    unsigned r = (u + 0x7FFFu + ((u >> 16) & 1u)) >> 16;
    return (unsigned short)r;
}

__device__ __forceinline__ unsigned cvtpk(float a, float b) {
    unsigned r;
    asm("v_cvt_pk_bf16_f32 %0, %1, %2" : "=v"(r) : "v"(a), "v"(b));
    return r;
}

__device__ __forceinline__ void gll16(const void* g, void* l) {
    __builtin_amdgcn_global_load_lds(
        (const __attribute__((address_space(1))) unsigned int*)g,
        (__attribute__((address_space(3))) unsigned int*)l, 16, 0, 0);
}

// ---- L1: Gram blocks FIRST (0..15, one block/head, 4-wave e-split + LDS reduce)
//          | rowsums (16..47) | cast-swizzle x (48..4143) ----
__global__ __launch_bounds__(256) void k_prep(const float* __restrict__ x,
                                              const float* __restrict__ emb,
                                              unsigned short* __restrict__ xb,
                                              float* __restrict__ G,
                                              float* __restrict__ rs) {
    int bid = blockIdx.x, tid = threadIdx.x;
    if (bid < 16) {
        // Gram: G[h][d1][d2] = sum_e K[d1,e]*K[d2,e]; wave w covers e in [w*512,(w+1)*512)
        __shared__ float red[4][1024];           // 16 KB, tile-by-tile reduce
        int lane = tid & 63, w = tid >> 6;
        int hi = lane >> 5, lo = lane & 31;
        int h = bid;
        const float* base0 = emb + (size_t)(h * 64 + lo) * 2048;        // dt=0 rows
        const float* base1 = emb + (size_t)(h * 64 + 32 + lo) * 2048;   // dt=1 rows
        int e0 = w * 512 + hi * 8;

        f32x16 acc[2][2];
#pragma unroll
        for (int i = 0; i < 2; ++i)
#pragma unroll
            for (int j = 0; j < 2; ++j) acc[i][j] = (f32x16)0.f;

        float4 cA0 = *(const float4*)(base0 + e0);
        float4 cB0 = *(const float4*)(base0 + e0 + 4);
        float4 cA1 = *(const float4*)(base1 + e0);
        float4 cB1 = *(const float4*)(base1 + e0 + 4);
        for (int step = 0; step < 32; ++step) {
            float4 nA0, nB0, nA1, nB1;
            if (step < 31) {
                int en = e0 + (step + 1) * 16;
                nA0 = *(const float4*)(base0 + en);
                nB0 = *(const float4*)(base0 + en + 4);
                nA1 = *(const float4*)(base1 + en);
                nB1 = *(const float4*)(base1 + en + 4);
            }
            union U { unsigned u[4]; bf16x8 v; } fr[2];
            fr[0].u[0] = cvtpk(cA0.x, cA0.y); fr[0].u[1] = cvtpk(cA0.z, cA0.w);
            fr[0].u[2] = cvtpk(cB0.x, cB0.y); fr[0].u[3] = cvtpk(cB0.z, cB0.w);
            fr[1].u[0] = cvtpk(cA1.x, cA1.y); fr[1].u[1] = cvtpk(cA1.z, cA1.w);
            fr[1].u[2] = cvtpk(cB1.x, cB1.y); fr[1].u[3] = cvtpk(cB1.z, cB1.w);
#pragma unroll
            for (int dA = 0; dA < 2; ++dA)
#pragma unroll
                for (int dB = 0; dB < 2; ++dB)
                    acc[dA][dB] = __builtin_amdgcn_mfma_f32_32x32x16_bf16(
                        fr[dA].v, fr[dB].v, acc[dA][dB], 0, 0, 0);
            cA0 = nA0; cB0 = nB0; cA1 = nA1; cB1 = nB1;
        }
#pragma unroll
        for (int tile = 0; tile < 4; ++tile) {
            int dA = tile >> 1, dB = tile & 1;
            __syncthreads();
#pragma unroll
            for (int r = 0; r < 16; ++r) red[w][r * 64 + lane] = acc[dA][dB][r];
            __syncthreads();
#pragma unroll
            for (int k = 0; k < 4; ++k) {
                int i = tid + k * 256;
                float s = red[0][i] + red[1][i] + red[2][i] + red[3][i];
                int r = i >> 6, li = i & 63;
                int d1 = dA * 32 + (r & 3) + 8 * (r >> 2) + 4 * (li >> 5);
                int d2 = dB * 32 + (li & 31);
                G[h * 4096 + d1 * 64 + d2] = s;
            }
        }
    } else if (bid < 48) {
        // rowsums rs[row] = sum_e emb[row][e]; 32 blocks x 32 rows
        int lane = tid & 63, w = tid >> 6;
        const float4* e4 = (const float4*)emb;
#pragma unroll
        for (int rr = 0; rr < 8; ++rr) {
            int row = (bid - 16) * 32 + w * 8 + rr;
            float s = 0.f;
#pragma unroll
            for (int i = 0; i < 8; ++i) {
                float4 t = e4[(size_t)row * 512 + i * 64 + lane];
                s += t.x + t.y + t.z + t.w;
            }
#pragma unroll
            for (int m = 32; m; m >>= 1) s += __shfl_xor(s, m, 64);
            if (lane == 0) rs[row] = s;
        }
    } else {
        // cast + XOR-swizzle x -> bf16
        int t = (bid - 48) * 256 + tid;
        int row = t >> 7;
        int c8  = t & 127;
        int colbyte = c8 * 16;
        const float4* s4 = (const float4*)(x + (size_t)row * 1024 + c8 * 8);
        float4 a = s4[0], b = s4[1];
        unsigned short tmp[8];
        tmp[0] = f2bf(a.x); tmp[1] = f2bf(a.y); tmp[2] = f2bf(a.z); tmp[3] = f2bf(a.w);
        tmp[4] = f2bf(b.x); tmp[5] = f2bf(b.y); tmp[6] = f2bf(b.z); tmp[7] = f2bf(b.w);
        int dstbyte = (colbyte & ~127) | ((colbyte & 127) ^ ((row & 7) << 4));
        *(uint4*)((char*)xb + (size_t)row * 2048 + dstbyte) = *(const uint4*)tmp;
    }
}

// ---- L2: W''[n][k] = (1/32) sum_d' W[h64+d'][k]*G[h][d'][d]  (bf16, swizzled)
//          + b''[n] = 0.5*rs[n] + (1/32) sum_d' pb[h64+d']*G[h][d'][d] ----
__global__ __launch_bounds__(256) void k_wpp(const float* __restrict__ W,
                                             const float* __restrict__ G,
                                             const float* __restrict__ pb,
                                             const float* __restrict__ rs,
                                             unsigned short* __restrict__ wbpp,
                                             float* __restrict__ bpp) {
    int bid = blockIdx.x, tid = threadIdx.x;
    if (bid < 128) {
        int lane = tid & 63, w = tid >> 6;
        int wt = bid * 4 + w;                  // 512 wave-tasks
        int h = wt >> 5, nt = wt & 31;
        int hi = lane >> 5, lo = lane & 31;
        union U { unsigned u[4]; bf16x8 v; } af[2][4], bfr[4];
#pragma unroll
        for (int mt = 0; mt < 2; ++mt)
#pragma unroll
            for (int ks = 0; ks < 4; ++ks) {
                float g[8];
#pragma unroll
                for (int j = 0; j < 8; ++j)
                    g[j] = G[h * 4096 + (ks * 16 + hi * 8 + j) * 64 + mt * 32 + lo] * 0.03125f;
                af[mt][ks].u[0] = cvtpk(g[0], g[1]); af[mt][ks].u[1] = cvtpk(g[2], g[3]);
                af[mt][ks].u[2] = cvtpk(g[4], g[5]); af[mt][ks].u[3] = cvtpk(g[6], g[7]);
            }
#pragma unroll
        for (int ks = 0; ks < 4; ++ks) {
            float b[8];
#pragma unroll
            for (int j = 0; j < 8; ++j)
                b[j] = W[(size_t)(h * 64 + ks * 16 + hi * 8 + j) * 1024 + nt * 32 + lo];
            bfr[ks].u[0] = cvtpk(b[0], b[1]); bfr[ks].u[1] = cvtpk(b[2], b[3]);
            bfr[ks].u[2] = cvtpk(b[4], b[5]); bfr[ks].u[3] = cvtpk(b[6], b[7]);
        }
        f32x16 acc[2];
#pragma unroll
        for (int mt = 0; mt < 2; ++mt) acc[mt] = (f32x16)0.f;
#pragma unroll
        for (int mt = 0; mt < 2; ++mt)
#pragma unroll
            for (int ks = 0; ks < 4; ++ks)
                acc[mt] = __builtin_amdgcn_mfma_f32_32x32x16_bf16(
                    af[mt][ks].v, bfr[ks].v, acc[mt], 0, 0, 0);
#pragma unroll
        for (int mt = 0; mt < 2; ++mt)
#pragma unroll
            for (int r = 0; r < 16; ++r) {
                int d = mt * 32 + (r & 3) + 8 * (r >> 2) + 4 * hi;
                int nrow = h * 64 + d;
                int k = nt * 32 + lo;
                int colbyte = k * 2;
                int byte = (colbyte & ~127) | ((colbyte & 127) ^ ((nrow & 7) << 4));
                *(unsigned short*)((char*)wbpp + (size_t)nrow * 2048 + byte) =
                    f2bf(acc[mt][r]);
            }
    } else {
        int n = (bid - 128) * 256 + tid;       // 0..1023
        int h = n >> 6, d = n & 63;
        float s = 0.f;
        for (int dp = 0; dp < 64; ++dp)
            s += pb[h * 64 + dp] * G[h * 4096 + dp * 64 + d];
        bpp[n] = 0.03125f * s + 0.5f * rs[n];
    }
}

// ---- L3: out = x @ W''^T + b''  (f32 out), m97-style 128x128 GEMM ----
__global__ __launch_bounds__(256) void k_final(const unsigned short* __restrict__ xb,
                                               const unsigned short* __restrict__ wb,
                                               const float* __restrict__ bias,
                                               float* __restrict__ O) {
    __shared__ alignas(16) short As[128 * 64];
    __shared__ alignas(16) short Bs[128 * 64];
    int tid = threadIdx.x;
    int lane = tid & 63, w = tid >> 6;
    int q = lane >> 4, c = lane & 15;
    int nt = blockIdx.x & 7, mt = blockIdx.x >> 3;
    int m0 = mt * 128, n0 = nt * 128;
    int wm = w >> 1, wn = w & 1;

    f32x4 acc[4][4];
#pragma unroll
    for (int i = 0; i < 4; ++i)
#pragma unroll
        for (int j = 0; j < 4; ++j) acc[i][j] = (f32x4)0.f;

    for (int kt = 0; kt < F_ / 64; ++kt) {
        int k0b = kt * 128;
#pragma unroll
        for (int p = 0; p < 4; ++p) {
            int o = (tid + p * 256) * 16;
            int r = o >> 7, cb = o & 127;
            gll16((const char*)xb + (size_t)(m0 + r) * 2048 + k0b + cb, (char*)As + o);
        }
#pragma unroll
        for (int p = 0; p < 4; ++p) {
            int o = (tid + p * 256) * 16;
            int r = o >> 7, cb = o & 127;
            gll16((const char*)wb + (size_t)(n0 + r) * 2048 + k0b + cb, (char*)Bs + o);
        }
        __syncthreads();

        bf16x8 af[4][2], bfr[4][2];
#pragma unroll
        for (int mf = 0; mf < 4; ++mf)
#pragma unroll
            for (int ks = 0; ks < 2; ++ks) {
                int r  = wm * 64 + mf * 16 + c;
                int kb = (16 * q + 64 * ks) ^ ((r & 7) << 4);
                af[mf][ks] = *(const bf16x8*)((const char*)As + r * 128 + kb);
            }
#pragma unroll
        for (int nf = 0; nf < 4; ++nf)
#pragma unroll
            for (int ks = 0; ks < 2; ++ks) {
                int r  = wn * 64 + nf * 16 + c;
                int kb = (16 * q + 64 * ks) ^ ((r & 7) << 4);
                bfr[nf][ks] = *(const bf16x8*)((const char*)Bs + r * 128 + kb);
            }
#pragma unroll
        for (int ks = 0; ks < 2; ++ks)
#pragma unroll
            for (int mf = 0; mf < 4; ++mf)
#pragma unroll
                for (int nf = 0; nf < 4; ++nf)
                    acc[mf][nf] = __builtin_amdgcn_mfma_f32_16x16x32_bf16(
                        af[mf][ks], bfr[nf][ks], acc[mf][nf], 0, 0, 0);
        __syncthreads();
    }

#pragma unroll
    for (int mf = 0; mf < 4; ++mf)
#pragma unroll
        for (int nf = 0; nf < 4; ++nf) {
            int n = n0 + wn * 64 + nf * 16 + c;
            float bv = bias[n];
#pragma unroll
            for (int r = 0; r < 4; ++r) {
                int m = m0 + wm * 64 + mf * 16 + q * 4 + r;
                O[(size_t)m * F_ + n] = acc[mf][nf][r] + bv;
            }
        }
}

extern "C" void kernel_launch(void* const* d_in, const int* in_sizes, int n_in,
                              void* d_out, int out_size, void* d_ws, size_t ws_size,
                              hipStream_t stream) {
    const float* x   = (const float*)d_in[0];
    const float* pw  = (const float*)d_in[1];
    const float* pb  = (const float*)d_in[2];
    const float* emb = (const float*)d_in[3];

    char* ws = (char*)d_ws;
    unsigned short* xb   = (unsigned short*)(ws);                 // 16 MB, swizzled bf16 x
    unsigned short* wbpp = (unsigned short*)(ws + 16777216);      //  2 MB, swizzled bf16 W''
    float*          G    = (float*)(ws + 18874368);               // 256 KB Gram (f32)
    float*          rs   = (float*)(ws + 19136512);               //  4 KB rowsums
    float*          bpp  = (float*)(ws + 19140608);               //  4 KB b''

    k_prep<<<4144, 256, 0, stream>>>(x, emb, xb, G, rs);
    k_wpp<<<132, 256, 0, stream>>>(pw, G, pb, rs, wbpp, bpp);
    k_final<<<512, 256, 0, stream>>>(xb, wbpp, bpp, (float*)d_out);
}